// Round 1
// baseline (372.027 us; speedup 1.0000x reference)
//
#include <hip/hip_runtime.h>
#include <cstdint>
#include <cstddef>

// Problem constants: B=4, S=2048, D=1024, H=4096, M = B*S = 8192.
#define MROWS 8192
#define DDIM  1024
#define HDIM  4096

typedef __bf16 bf16x8 __attribute__((ext_vector_type(8)));
typedef float  f32x4  __attribute__((ext_vector_type(4)));

typedef __attribute__((address_space(1))) void* as1_vp;
typedef __attribute__((address_space(3))) void* as3_vp;

__device__ __forceinline__ unsigned short f2bf(float f) {
  unsigned int u = __builtin_bit_cast(unsigned int, f);
  u += 0x7fffu + ((u >> 16) & 1u);   // RNE
  return (unsigned short)(u >> 16);
}
__device__ __forceinline__ float bf2f(unsigned short h) {
  return __builtin_bit_cast(float, (unsigned int)h << 16);
}

// async global->LDS, 16B per lane; lds base must be wave-uniform (HW adds lane*16)
__device__ __forceinline__ void gld_lds16(const unsigned short* g, unsigned short* lds) {
  __builtin_amdgcn_global_load_lds((as1_vp)(uintptr_t)g, (as3_vp)lds, 16, 0, 0);
}

// fp32 -> bf16 convert, 4 elems/thread
__global__ __launch_bounds__(256) void cvt_kernel(const float* __restrict__ src,
                                                  unsigned short* __restrict__ dst, int n4) {
  int i = blockIdx.x * 256 + threadIdx.x;
  if (i < n4) {
    float4 v = ((const float4*)src)[i];
    ushort4 o;
    o.x = f2bf(v.x); o.y = f2bf(v.y); o.z = f2bf(v.z); o.w = f2bf(v.w);
    ((ushort4*)dst)[i] = o;
  }
}

// p1[m,i] = dot(x[m,:], x[b, 2+2i, :]),  i<4, b = m>>11. One block per row m.
__global__ __launch_bounds__(256) void p1_kernel(const float* __restrict__ x,
                                                 float* __restrict__ p1) {
  const int m = blockIdx.x;
  const int b = m >> 11;
  const float* xrow = x + (size_t)m * DDIM;
  const float* od   = x + ((size_t)b * 2048 + 2) * DDIM;  // odd token i at +i*2048
  float a0 = 0.f, a1 = 0.f, a2 = 0.f, a3 = 0.f;
  for (int d = threadIdx.x; d < DDIM; d += 256) {
    float xv = xrow[d];
    a0 += xv * od[d];
    a1 += xv * od[2048 + d];
    a2 += xv * od[4096 + d];
    a3 += xv * od[6144 + d];
  }
#pragma unroll
  for (int off = 32; off > 0; off >>= 1) {
    a0 += __shfl_down(a0, off);
    a1 += __shfl_down(a1, off);
    a2 += __shfl_down(a2, off);
    a3 += __shfl_down(a3, off);
  }
  __shared__ float red[4][4];
  const int wave = threadIdx.x >> 6, lane = threadIdx.x & 63;
  if (lane == 0) { red[wave][0] = a0; red[wave][1] = a1; red[wave][2] = a2; red[wave][3] = a3; }
  __syncthreads();
  if (threadIdx.x < 4)
    p1[(size_t)m * 4 + threadIdx.x] =
        red[0][threadIdx.x] + red[1][threadIdx.x] + red[2][threadIdx.x] + red[3][threadIdx.x];
}

// p2[m, i*4+r] = dot(hact[m, r*1024 : (r+1)*1024], x[b, 10+2i, :]). One block per row m.
__global__ __launch_bounds__(256) void p2_kernel(const unsigned short* __restrict__ hact,
                                                 const float* __restrict__ x,
                                                 float* __restrict__ p2) {
  const int m = blockIdx.x;
  const int b = m >> 11;
  const unsigned short* hrow = hact + (size_t)m * HDIM;
  const float* od = x + ((size_t)b * 2048 + 10) * DDIM;  // odd token 4+i at +i*2048
  float acc[4][4] = {{0.f}};
  for (int d = threadIdx.x; d < DDIM; d += 256) {
    float h0 = bf2f(hrow[d]);
    float h1 = bf2f(hrow[1024 + d]);
    float h2 = bf2f(hrow[2048 + d]);
    float h3 = bf2f(hrow[3072 + d]);
#pragma unroll
    for (int i = 0; i < 4; ++i) {
      float ov = od[i * 2048 + d];
      acc[i][0] += ov * h0; acc[i][1] += ov * h1;
      acc[i][2] += ov * h2; acc[i][3] += ov * h3;
    }
  }
#pragma unroll
  for (int i = 0; i < 4; ++i)
#pragma unroll
    for (int r = 0; r < 4; ++r)
#pragma unroll
      for (int off = 32; off > 0; off >>= 1)
        acc[i][r] += __shfl_down(acc[i][r], off);
  __shared__ float red[4][16];
  const int wave = threadIdx.x >> 6, lane = threadIdx.x & 63;
  if (lane == 0) {
#pragma unroll
    for (int i = 0; i < 4; ++i)
#pragma unroll
      for (int r = 0; r < 4; ++r) red[wave][i * 4 + r] = acc[i][r];
  }
  __syncthreads();
  if (threadIdx.x < 16)
    p2[(size_t)m * 16 + threadIdx.x] = red[0][threadIdx.x] + red[1][threadIdx.x] +
                                       red[2][threadIdx.x] + red[3][threadIdx.x];
}

// m97-style mainloop: C(128x128) = A(128xK) . B(128xK)^T, bf16 in, fp32 acc.
// 256 threads = 4 waves, each wave a 64x64 subtile = 4x4 MFMA 16x16x32 tiles.
__device__ __forceinline__ void gemm_bt_tile(const unsigned short* __restrict__ A,
                                             const unsigned short* __restrict__ B,
                                             const int K, const int m0, const int n0,
                                             unsigned short* As, unsigned short* Bs,
                                             f32x4 acc[4][4]) {
  const int tid  = threadIdx.x;
  const int wave = tid >> 6;
  const int lane = tid & 63;
  const int quad = lane >> 4;
  const int l16  = lane & 15;
  const int wm   = (wave >> 1) * 64;
  const int wn   = (wave & 1) * 64;

  // staging: 512 16B-chunks per tile (128 rows x 4 chunks); 2 wave-loads per wave
  const int c0 = (wave * 2 + 0) * 64 + lane;
  const int c1 = (wave * 2 + 1) * 64 + lane;
  const unsigned short* gA0 = A + (size_t)(m0 + (c0 >> 2)) * K + (c0 & 3) * 8;
  const unsigned short* gA1 = A + (size_t)(m0 + (c1 >> 2)) * K + (c1 & 3) * 8;
  const unsigned short* gB0 = B + (size_t)(n0 + (c0 >> 2)) * K + (c0 & 3) * 8;
  const unsigned short* gB1 = B + (size_t)(n0 + (c1 >> 2)) * K + (c1 & 3) * 8;
  unsigned short* lA0 = As + (wave * 2 + 0) * 512;
  unsigned short* lA1 = As + (wave * 2 + 1) * 512;
  unsigned short* lB0 = Bs + (wave * 2 + 0) * 512;
  unsigned short* lB1 = Bs + (wave * 2 + 1) * 512;

  for (int k0 = 0; k0 < K; k0 += 32) {
    __syncthreads();               // previous compute done before LDS overwrite
    gld_lds16(gA0 + k0, lA0);
    gld_lds16(gA1 + k0, lA1);
    gld_lds16(gB0 + k0, lB0);
    gld_lds16(gB1 + k0, lB1);
    __syncthreads();               // compiler drains vmcnt before s_barrier
    bf16x8 a[4], b[4];
#pragma unroll
    for (int i = 0; i < 4; ++i) {
      a[i] = *(const bf16x8*)(As + (wm + i * 16 + l16) * 32 + quad * 8);
      b[i] = *(const bf16x8*)(Bs + (wn + i * 16 + l16) * 32 + quad * 8);
    }
#pragma unroll
    for (int i = 0; i < 4; ++i)
#pragma unroll
      for (int j = 0; j < 4; ++j)
        acc[i][j] = __builtin_amdgcn_mfma_f32_16x16x32_bf16(a[i], b[j], acc[i][j], 0, 0, 0);
  }
}

// GEMM1: hact = gelu( x.W1^T + b1 + scale*p1*even ),  M=8192 N=4096 K=1024, out bf16
__global__ __launch_bounds__(256) void gemm1_kernel(
    const unsigned short* __restrict__ xb, const unsigned short* __restrict__ w1b,
    const float* __restrict__ x, const float* __restrict__ b1,
    const float* __restrict__ p1, const float* __restrict__ scale_p,
    unsigned short* __restrict__ hact) {
  __shared__ __align__(16) unsigned short As[128 * 32];
  __shared__ __align__(16) unsigned short Bs[128 * 32];
  const int n0 = blockIdx.x * 128;
  const int m0 = blockIdx.y * 128;
  f32x4 acc[4][4];
  const f32x4 z = {0.f, 0.f, 0.f, 0.f};
#pragma unroll
  for (int i = 0; i < 4; ++i)
#pragma unroll
    for (int j = 0; j < 4; ++j) acc[i][j] = z;

  gemm_bt_tile(xb, w1b, DDIM, m0, n0, As, Bs, acc);

  const int tid = threadIdx.x;
  const int wave = tid >> 6, lane = tid & 63, quad = lane >> 4, l16 = lane & 15;
  const int wm = (wave >> 1) * 64, wn = (wave & 1) * 64;
  const float sc = scale_p[0];
  const int bidx = m0 >> 11;                 // batch (128 | 2048 so uniform per block)
  const int i1 = (n0 + wn) >> 10;            // wave-uniform lora index
  const float* exrow = x + ((size_t)(bidx * 2048 + 1 + 2 * i1)) * DDIM;

  float exv[4], b1v[4]; int nn[4];
#pragma unroll
  for (int j = 0; j < 4; ++j) {
    nn[j]  = n0 + wn + j * 16 + l16;
    exv[j] = exrow[nn[j] & 1023];
    b1v[j] = b1[nn[j]];
  }
#pragma unroll
  for (int i = 0; i < 4; ++i) {
#pragma unroll
    for (int r = 0; r < 4; ++r) {
      const int m = m0 + wm + i * 16 + quad * 4 + r;
      const float pv = p1[(size_t)m * 4 + i1] * sc;
#pragma unroll
      for (int j = 0; j < 4; ++j) {
        float v = acc[i][j][r] + b1v[j] + pv * exv[j];
        float g = 0.5f * v * (1.0f + erff(v * 0.70710678118654752f));  // exact gelu
        hact[(size_t)m * HDIM + nn[j]] = f2bf(g);
      }
    }
  }
}

// GEMM2: out = hact.W2^T + b2 + scale * sum_r even2[4q+r]*p2[m,i2,r],  M=8192 N=1024 K=4096
__global__ __launch_bounds__(256) void gemm2_kernel(
    const unsigned short* __restrict__ hact, const unsigned short* __restrict__ w2b,
    const float* __restrict__ x, const float* __restrict__ b2,
    const float* __restrict__ p2, const float* __restrict__ scale_p,
    float* __restrict__ out) {
  __shared__ __align__(16) unsigned short As[128 * 32];
  __shared__ __align__(16) unsigned short Bs[128 * 32];
  const int n0 = blockIdx.x * 128;
  const int m0 = blockIdx.y * 128;
  f32x4 acc[4][4];
  const f32x4 z = {0.f, 0.f, 0.f, 0.f};
#pragma unroll
  for (int i = 0; i < 4; ++i)
#pragma unroll
    for (int j = 0; j < 4; ++j) acc[i][j] = z;

  gemm_bt_tile(hact, w2b, HDIM, m0, n0, As, Bs, acc);

  const int tid = threadIdx.x;
  const int wave = tid >> 6, lane = tid & 63, quad = lane >> 4, l16 = lane & 15;
  const int wm = (wave >> 1) * 64, wn = (wave & 1) * 64;
  const float sc = scale_p[0];
  const int bidx = m0 >> 11;
  const int i2 = (n0 + wn) >> 8;             // wave-uniform
  const float* evrow = x + ((size_t)(bidx * 2048 + 9 + 2 * i2)) * DDIM;

  float4 ev[4]; float b2v[4]; int nn[4];
#pragma unroll
  for (int j = 0; j < 4; ++j) {
    nn[j] = n0 + wn + j * 16 + l16;
    const int q = nn[j] & 255;
    ev[j]  = *(const float4*)(evrow + 4 * q);
    b2v[j] = b2[nn[j]];
  }
#pragma unroll
  for (int i = 0; i < 4; ++i) {
#pragma unroll
    for (int r = 0; r < 4; ++r) {
      const int m = m0 + wm + i * 16 + quad * 4 + r;
      const float4 pv = *(const float4*)(p2 + (size_t)m * 16 + i2 * 4);
#pragma unroll
      for (int j = 0; j < 4; ++j) {
        float lora = ev[j].x * pv.x + ev[j].y * pv.y + ev[j].z * pv.z + ev[j].w * pv.w;
        out[(size_t)m * DDIM + nn[j]] = acc[i][j][r] + b2v[j] + sc * lora;
      }
    }
  }
}

extern "C" void kernel_launch(void* const* d_in, const int* in_sizes, int n_in,
                              void* d_out, int out_size, void* d_ws, size_t ws_size,
                              hipStream_t stream) {
  const float* x     = (const float*)d_in[0];
  const float* W1    = (const float*)d_in[1];
  const float* b1    = (const float*)d_in[2];
  const float* W2    = (const float*)d_in[3];
  const float* b2    = (const float*)d_in[4];
  const float* scale = (const float*)d_in[5];
  float* out = (float*)d_out;

  char* ws = (char*)d_ws;
  unsigned short* xb   = (unsigned short*)(ws);                // 16 MiB
  unsigned short* w1b  = (unsigned short*)(ws + 16777216);     //  8 MiB
  unsigned short* w2b  = (unsigned short*)(ws + 25165824);     //  8 MiB
  unsigned short* hact = (unsigned short*)(ws + 33554432);     // 64 MiB
  float*          p1   = (float*)(ws + 100663296);             // 128 KiB
  float*          p2   = (float*)(ws + 100794368);             // 512 KiB
  // total 101,318,656 bytes

  cvt_kernel<<<dim3((MROWS * DDIM) / 1024), dim3(256), 0, stream>>>(x, xb, (MROWS * DDIM) / 4);
  cvt_kernel<<<dim3((HDIM * DDIM) / 1024), dim3(256), 0, stream>>>(W1, w1b, (HDIM * DDIM) / 4);
  cvt_kernel<<<dim3((DDIM * HDIM) / 1024), dim3(256), 0, stream>>>(W2, w2b, (DDIM * HDIM) / 4);
  p1_kernel<<<dim3(MROWS), dim3(256), 0, stream>>>(x, p1);
  gemm1_kernel<<<dim3(HDIM / 128, MROWS / 128), dim3(256), 0, stream>>>(xb, w1b, x, b1, p1, scale, hact);
  p2_kernel<<<dim3(MROWS), dim3(256), 0, stream>>>(hact, x, p2);
  gemm2_kernel<<<dim3(DDIM / 128, MROWS / 128), dim3(256), 0, stream>>>(hact, w2b, x, b2, p2, scale, out);
}

// Round 2
// 358.869 us; speedup vs baseline: 1.0367x; 1.0367x over previous
//
#include <hip/hip_runtime.h>
#include <cstdint>
#include <cstddef>

// Problem constants: B=4, S=2048, D=1024, H=4096, M = B*S = 8192.
#define MROWS 8192
#define DDIM  1024
#define HDIM  4096

typedef __bf16 bf16x8 __attribute__((ext_vector_type(8)));
typedef float  f32x4  __attribute__((ext_vector_type(4)));

typedef __attribute__((address_space(1))) void* as1_vp;
typedef __attribute__((address_space(3))) void* as3_vp;

__device__ __forceinline__ unsigned short f2bf(float f) {
  unsigned int u = __builtin_bit_cast(unsigned int, f);
  u += 0x7fffu + ((u >> 16) & 1u);   // RNE
  return (unsigned short)(u >> 16);
}
__device__ __forceinline__ float bf2f(unsigned short h) {
  return __builtin_bit_cast(float, (unsigned int)h << 16);
}

// fast gelu: tanh-form, exp2+rcp based. |err vs exact erf-gelu| < ~1e-3,
// far under the bf16-floored threshold margin. Saturates correctly at +-inf.
__device__ __forceinline__ float fast_gelu(float x) {
  float x3 = x * x * x;
  float z = 0.7978845608028654f * x + 0.03567740814f * x3;  // sqrt(2/pi)*(x+0.044715x^3)
  float e = __builtin_amdgcn_exp2f(z * 2.8853900817779268f); // exp(2z)
  float t = 1.0f - 2.0f * __builtin_amdgcn_rcpf(e + 1.0f);   // tanh(z)
  return 0.5f * x * (1.0f + t);
}

// async global->LDS, 16B per lane; lds base must be wave-uniform (HW adds lane*16)
__device__ __forceinline__ void gld_lds16(const unsigned short* g, unsigned short* lds) {
  __builtin_amdgcn_global_load_lds((as1_vp)(uintptr_t)g, (as3_vp)lds, 16, 0, 0);
}

// fp32 -> bf16 convert for x, W1, W2 in one launch. Grid sized exactly:
// x: 2097152 float4 groups, W1: 1048576, W2: 1048576 -> 4194304 total.
__global__ __launch_bounds__(256) void cvt3_kernel(
    const float* __restrict__ x, const float* __restrict__ w1,
    const float* __restrict__ w2, unsigned short* __restrict__ xb,
    unsigned short* __restrict__ w1b, unsigned short* __restrict__ w2b) {
  int i = blockIdx.x * 256 + threadIdx.x;
  const float* src; unsigned short* dst; int off;
  if (i < 2097152)      { src = x;  dst = xb;  off = i; }
  else if (i < 3145728) { src = w1; dst = w1b; off = i - 2097152; }
  else                  { src = w2; dst = w2b; off = i - 3145728; }
  float4 v = ((const float4*)src)[off];
  ushort4 o;
  o.x = f2bf(v.x); o.y = f2bf(v.y); o.z = f2bf(v.z); o.w = f2bf(v.w);
  ((ushort4*)dst)[off] = o;
}

// p1[m,i] = dot(x[m,:], x[b, 2+2i, :]),  i<4, b = m>>11. One block per row m.
__global__ __launch_bounds__(256) void p1_kernel(const float* __restrict__ x,
                                                 float* __restrict__ p1) {
  const int m = blockIdx.x;
  const int b = m >> 11;
  const float* xrow = x + (size_t)m * DDIM;
  const float* od   = x + ((size_t)b * 2048 + 2) * DDIM;  // odd token i at +i*2048
  float a0 = 0.f, a1 = 0.f, a2 = 0.f, a3 = 0.f;
  for (int d = threadIdx.x; d < DDIM; d += 256) {
    float xv = xrow[d];
    a0 += xv * od[d];
    a1 += xv * od[2048 + d];
    a2 += xv * od[4096 + d];
    a3 += xv * od[6144 + d];
  }
#pragma unroll
  for (int off = 32; off > 0; off >>= 1) {
    a0 += __shfl_down(a0, off);
    a1 += __shfl_down(a1, off);
    a2 += __shfl_down(a2, off);
    a3 += __shfl_down(a3, off);
  }
  __shared__ float red[4][4];
  const int wave = threadIdx.x >> 6, lane = threadIdx.x & 63;
  if (lane == 0) { red[wave][0] = a0; red[wave][1] = a1; red[wave][2] = a2; red[wave][3] = a3; }
  __syncthreads();
  if (threadIdx.x < 4)
    p1[(size_t)m * 4 + threadIdx.x] =
        red[0][threadIdx.x] + red[1][threadIdx.x] + red[2][threadIdx.x] + red[3][threadIdx.x];
}

// p2[m, i*4+r] = dot(hact[m, r*1024 : (r+1)*1024], x[b, 10+2i, :]). One block per row m.
__global__ __launch_bounds__(256) void p2_kernel(const unsigned short* __restrict__ hact,
                                                 const float* __restrict__ x,
                                                 float* __restrict__ p2) {
  const int m = blockIdx.x;
  const int b = m >> 11;
  const unsigned short* hrow = hact + (size_t)m * HDIM;
  const float* od = x + ((size_t)b * 2048 + 10) * DDIM;  // odd token 4+i at +i*2048
  float acc[4][4] = {{0.f}};
  for (int d = threadIdx.x; d < DDIM; d += 256) {
    float h0 = bf2f(hrow[d]);
    float h1 = bf2f(hrow[1024 + d]);
    float h2 = bf2f(hrow[2048 + d]);
    float h3 = bf2f(hrow[3072 + d]);
#pragma unroll
    for (int i = 0; i < 4; ++i) {
      float ov = od[i * 2048 + d];
      acc[i][0] += ov * h0; acc[i][1] += ov * h1;
      acc[i][2] += ov * h2; acc[i][3] += ov * h3;
    }
  }
#pragma unroll
  for (int i = 0; i < 4; ++i)
#pragma unroll
    for (int r = 0; r < 4; ++r)
#pragma unroll
      for (int off = 32; off > 0; off >>= 1)
        acc[i][r] += __shfl_down(acc[i][r], off);
  __shared__ float red[4][16];
  const int wave = threadIdx.x >> 6, lane = threadIdx.x & 63;
  if (lane == 0) {
#pragma unroll
    for (int i = 0; i < 4; ++i)
#pragma unroll
      for (int r = 0; r < 4; ++r) red[wave][i * 4 + r] = acc[i][r];
  }
  __syncthreads();
  if (threadIdx.x < 16)
    p2[(size_t)m * 16 + threadIdx.x] = red[0][threadIdx.x] + red[1][threadIdx.x] +
                                       red[2][threadIdx.x] + red[3][threadIdx.x];
}

// m97-style mainloop: C(128x128) = A(128xK) . B(128xK)^T, bf16 in, fp32 acc.
// 256 threads = 4 waves, each wave a 64x64 subtile = 4x4 MFMA 16x16x32 tiles.
//
// LDS chunk swizzle: the 16B chunk stored at LDS slot (row r, slot s) is global
// chunk ch = (s - (r>>1)) & 3 of row r. Implemented by permuting each lane's
// GLOBAL source pointer (global_load_lds destinations are forced contiguous).
// Readers use slot s = (quad + (r>>1)) & 3, spreading the b128 reads across
// all 8 bank-quads instead of 2.
__device__ __forceinline__ void gemm_bt_tile(const unsigned short* __restrict__ A,
                                             const unsigned short* __restrict__ B,
                                             const int K, const int m0, const int n0,
                                             unsigned short* As, unsigned short* Bs,
                                             f32x4 acc[4][4]) {
  const int tid  = threadIdx.x;
  const int wave = tid >> 6;
  const int lane = tid & 63;
  const int quad = lane >> 4;
  const int l16  = lane & 15;
  const int wm   = (wave >> 1) * 64;
  const int wn   = (wave & 1) * 64;

  // staging: 512 16B-slots per tile (128 rows x 4 slots); 2 wave-loads per wave
  const int c0 = wave * 128 + lane;
  const int c1 = c0 + 64;
  const int r0 = c0 >> 2, ch0 = ((c0 & 3) - (r0 >> 1)) & 3;
  const int r1 = c1 >> 2, ch1 = ((c1 & 3) - (r1 >> 1)) & 3;
  const unsigned short* gA0 = A + (size_t)(m0 + r0) * K + ch0 * 8;
  const unsigned short* gA1 = A + (size_t)(m0 + r1) * K + ch1 * 8;
  const unsigned short* gB0 = B + (size_t)(n0 + r0) * K + ch0 * 8;
  const unsigned short* gB1 = B + (size_t)(n0 + r1) * K + ch1 * 8;
  unsigned short* lA0 = As + (wave * 2 + 0) * 512;
  unsigned short* lA1 = As + (wave * 2 + 1) * 512;
  unsigned short* lB0 = Bs + (wave * 2 + 0) * 512;
  unsigned short* lB1 = Bs + (wave * 2 + 1) * 512;

  // read-side swizzled slot: (quad + (row>>1)) & 3; row>>1 mod 4 == (l16>>1) mod 4
  const int eq = (quad + (l16 >> 1)) & 3;

  for (int k0 = 0; k0 < K; k0 += 32) {
    __syncthreads();               // previous compute done before LDS overwrite
    gld_lds16(gA0 + k0, lA0);
    gld_lds16(gA1 + k0, lA1);
    gld_lds16(gB0 + k0, lB0);
    gld_lds16(gB1 + k0, lB1);
    __syncthreads();               // compiler drains vmcnt before s_barrier
    bf16x8 a[4], b[4];
#pragma unroll
    for (int i = 0; i < 4; ++i) {
      a[i] = *(const bf16x8*)(As + (wm + i * 16 + l16) * 32 + eq * 8);
      b[i] = *(const bf16x8*)(Bs + (wn + i * 16 + l16) * 32 + eq * 8);
    }
#pragma unroll
    for (int i = 0; i < 4; ++i)
#pragma unroll
      for (int j = 0; j < 4; ++j)
        acc[i][j] = __builtin_amdgcn_mfma_f32_16x16x32_bf16(a[i], b[j], acc[i][j], 0, 0, 0);
  }
}

// GEMM1: hact = gelu( x.W1^T + b1 + scale*p1*even ),  M=8192 N=4096 K=1024, out bf16
__global__ __launch_bounds__(256) void gemm1_kernel(
    const unsigned short* __restrict__ xb, const unsigned short* __restrict__ w1b,
    const float* __restrict__ x, const float* __restrict__ b1,
    const float* __restrict__ p1, const float* __restrict__ scale_p,
    unsigned short* __restrict__ hact) {
  __shared__ __align__(16) unsigned short As[128 * 32];
  __shared__ __align__(16) unsigned short Bs[128 * 32];
  const int n0 = blockIdx.x * 128;
  const int m0 = blockIdx.y * 128;
  f32x4 acc[4][4];
  const f32x4 z = {0.f, 0.f, 0.f, 0.f};
#pragma unroll
  for (int i = 0; i < 4; ++i)
#pragma unroll
    for (int j = 0; j < 4; ++j) acc[i][j] = z;

  gemm_bt_tile(xb, w1b, DDIM, m0, n0, As, Bs, acc);

  const int tid = threadIdx.x;
  const int wave = tid >> 6, lane = tid & 63, quad = lane >> 4, l16 = lane & 15;
  const int wm = (wave >> 1) * 64, wn = (wave & 1) * 64;
  const float sc = scale_p[0];
  const int bidx = m0 >> 11;                 // batch (128 | 2048 so uniform per block)
  const int i1 = (n0 + wn) >> 10;            // wave-uniform lora index
  const float* exrow = x + ((size_t)(bidx * 2048 + 1 + 2 * i1)) * DDIM;

  float exv[4], b1v[4]; int nn[4];
#pragma unroll
  for (int j = 0; j < 4; ++j) {
    nn[j]  = n0 + wn + j * 16 + l16;
    exv[j] = exrow[nn[j] & 1023];
    b1v[j] = b1[nn[j]];
  }
#pragma unroll
  for (int i = 0; i < 4; ++i) {
#pragma unroll
    for (int r = 0; r < 4; ++r) {
      const int m = m0 + wm + i * 16 + quad * 4 + r;
      const float pv = p1[(size_t)m * 4 + i1] * sc;
#pragma unroll
      for (int j = 0; j < 4; ++j) {
        float v = acc[i][j][r] + b1v[j] + pv * exv[j];
        hact[(size_t)m * HDIM + nn[j]] = f2bf(fast_gelu(v));
      }
    }
  }
}

// GEMM2: out = hact.W2^T + b2 + scale * sum_r even2[4q+r]*p2[m,i2,r],  M=8192 N=1024 K=4096
__global__ __launch_bounds__(256) void gemm2_kernel(
    const unsigned short* __restrict__ hact, const unsigned short* __restrict__ w2b,
    const float* __restrict__ x, const float* __restrict__ b2,
    const float* __restrict__ p2, const float* __restrict__ scale_p,
    float* __restrict__ out) {
  __shared__ __align__(16) unsigned short As[128 * 32];
  __shared__ __align__(16) unsigned short Bs[128 * 32];
  const int n0 = blockIdx.x * 128;
  const int m0 = blockIdx.y * 128;
  f32x4 acc[4][4];
  const f32x4 z = {0.f, 0.f, 0.f, 0.f};
#pragma unroll
  for (int i = 0; i < 4; ++i)
#pragma unroll
    for (int j = 0; j < 4; ++j) acc[i][j] = z;

  gemm_bt_tile(hact, w2b, HDIM, m0, n0, As, Bs, acc);

  const int tid = threadIdx.x;
  const int wave = tid >> 6, lane = tid & 63, quad = lane >> 4, l16 = lane & 15;
  const int wm = (wave >> 1) * 64, wn = (wave & 1) * 64;
  const float sc = scale_p[0];
  const int bidx = m0 >> 11;
  const int i2 = (n0 + wn) >> 8;             // wave-uniform
  const float* evrow = x + ((size_t)(bidx * 2048 + 9 + 2 * i2)) * DDIM;

  float4 ev[4]; float b2v[4]; int nn[4];
#pragma unroll
  for (int j = 0; j < 4; ++j) {
    nn[j] = n0 + wn + j * 16 + l16;
    const int q = nn[j] & 255;
    ev[j]  = *(const float4*)(evrow + 4 * q);
    b2v[j] = b2[nn[j]];
  }
#pragma unroll
  for (int i = 0; i < 4; ++i) {
#pragma unroll
    for (int r = 0; r < 4; ++r) {
      const int m = m0 + wm + i * 16 + quad * 4 + r;
      const float4 pv = *(const float4*)(p2 + (size_t)m * 16 + i2 * 4);
#pragma unroll
      for (int j = 0; j < 4; ++j) {
        float lora = ev[j].x * pv.x + ev[j].y * pv.y + ev[j].z * pv.z + ev[j].w * pv.w;
        out[(size_t)m * DDIM + nn[j]] = acc[i][j][r] + b2v[j] + sc * lora;
      }
    }
  }
}

extern "C" void kernel_launch(void* const* d_in, const int* in_sizes, int n_in,
                              void* d_out, int out_size, void* d_ws, size_t ws_size,
                              hipStream_t stream) {
  const float* x     = (const float*)d_in[0];
  const float* W1    = (const float*)d_in[1];
  const float* b1    = (const float*)d_in[2];
  const float* W2    = (const float*)d_in[3];
  const float* b2    = (const float*)d_in[4];
  const float* scale = (const float*)d_in[5];
  float* out = (float*)d_out;

  char* ws = (char*)d_ws;
  unsigned short* xb   = (unsigned short*)(ws);                // 16 MiB
  unsigned short* w1b  = (unsigned short*)(ws + 16777216);     //  8 MiB
  unsigned short* w2b  = (unsigned short*)(ws + 25165824);     //  8 MiB
  unsigned short* hact = (unsigned short*)(ws + 33554432);     // 64 MiB
  float*          p1   = (float*)(ws + 100663296);             // 128 KiB
  float*          p2   = (float*)(ws + 100794368);             // 512 KiB
  // total 101,318,656 bytes

  cvt3_kernel<<<dim3(16384), dim3(256), 0, stream>>>(x, W1, W2, xb, w1b, w2b);
  p1_kernel<<<dim3(MROWS), dim3(256), 0, stream>>>(x, p1);
  gemm1_kernel<<<dim3(HDIM / 128, MROWS / 128), dim3(256), 0, stream>>>(xb, w1b, x, b1, p1, scale, hact);
  p2_kernel<<<dim3(MROWS), dim3(256), 0, stream>>>(hact, x, p2);
  gemm2_kernel<<<dim3(DDIM / 128, MROWS / 128), dim3(256), 0, stream>>>(hact, w2b, x, b2, p2, scale, out);
}

// Round 3
// 289.726 us; speedup vs baseline: 1.2841x; 1.2387x over previous
//
#include <hip/hip_runtime.h>
#include <cstdint>
#include <cstddef>

// Problem constants: B=4, S=2048, D=1024, H=4096, M = B*S = 8192.
#define MROWS 8192
#define DDIM  1024
#define HDIM  4096

typedef __bf16 bf16x8 __attribute__((ext_vector_type(8)));
typedef float  f32x4  __attribute__((ext_vector_type(4)));

typedef __attribute__((address_space(1))) void* as1_vp;
typedef __attribute__((address_space(3))) void* as3_vp;

__device__ __forceinline__ unsigned short f2bf(float f) {
  unsigned int u = __builtin_bit_cast(unsigned int, f);
  u += 0x7fffu + ((u >> 16) & 1u);   // RNE
  return (unsigned short)(u >> 16);
}
__device__ __forceinline__ float bf2f(unsigned short h) {
  return __builtin_bit_cast(float, (unsigned int)h << 16);
}

// fast gelu: tanh-form, exp2+rcp based. |err vs exact erf-gelu| < ~1e-3.
__device__ __forceinline__ float fast_gelu(float x) {
  float x3 = x * x * x;
  float z = 0.7978845608028654f * x + 0.03567740814f * x3;
  float e = __builtin_amdgcn_exp2f(z * 2.8853900817779268f); // exp(2z)
  float t = 1.0f - 2.0f * __builtin_amdgcn_rcpf(e + 1.0f);   // tanh(z)
  return 0.5f * x * (1.0f + t);
}

__device__ __forceinline__ void gld_lds16(const unsigned short* g, unsigned short* lds) {
  __builtin_amdgcn_global_load_lds((as1_vp)(uintptr_t)g, (as3_vp)lds, 16, 0, 0);
}

// fp32 -> bf16 convert for W1, W2 (x handled by p1 kernel). 2*1048576 float4 groups.
__global__ __launch_bounds__(256) void cvt2_kernel(
    const float* __restrict__ w1, const float* __restrict__ w2,
    unsigned short* __restrict__ w1b, unsigned short* __restrict__ w2b) {
  int i = blockIdx.x * 256 + threadIdx.x;
  const float* src; unsigned short* dst; int off;
  if (i < 1048576) { src = w1; dst = w1b; off = i; }
  else             { src = w2; dst = w2b; off = i - 1048576; }
  float4 v = ((const float4*)src)[off];
  ushort4 o;
  o.x = f2bf(v.x); o.y = f2bf(v.y); o.z = f2bf(v.z); o.w = f2bf(v.w);
  ((ushort4*)dst)[off] = o;
}

// p1[m,i] = dot(x[m,:], x[b, 2+2i, :]), i<4; ALSO emits xb (bf16 of x).
// One wave per row m; block = 4 waves = 4 rows. Grid 2048.
__global__ __launch_bounds__(256) void p1_kernel(const float* __restrict__ x,
                                                 float* __restrict__ p1,
                                                 unsigned short* __restrict__ xb) {
  const int wave = threadIdx.x >> 6, lane = threadIdx.x & 63;
  const int m = blockIdx.x * 4 + wave;
  const int b = m >> 11;
  const float4* xrow4 = (const float4*)(x + (size_t)m * DDIM);
  const float4* od4   = (const float4*)(x + ((size_t)b * 2048 + 2) * DDIM);
  ushort4* xbrow4 = (ushort4*)(xb + (size_t)m * DDIM);
  float a0 = 0.f, a1 = 0.f, a2 = 0.f, a3 = 0.f;
#pragma unroll
  for (int it = 0; it < 4; ++it) {
    int g = it * 64 + lane;           // float4 group 0..255
    float4 v = xrow4[g];
    ushort4 o; o.x = f2bf(v.x); o.y = f2bf(v.y); o.z = f2bf(v.z); o.w = f2bf(v.w);
    xbrow4[g] = o;
    float4 o0 = od4[g];
    float4 o1 = od4[512 + g];
    float4 o2 = od4[1024 + g];
    float4 o3 = od4[1536 + g];
    a0 += v.x * o0.x + v.y * o0.y + v.z * o0.z + v.w * o0.w;
    a1 += v.x * o1.x + v.y * o1.y + v.z * o1.z + v.w * o1.w;
    a2 += v.x * o2.x + v.y * o2.y + v.z * o2.z + v.w * o2.w;
    a3 += v.x * o3.x + v.y * o3.y + v.z * o3.z + v.w * o3.w;
  }
#pragma unroll
  for (int off = 32; off > 0; off >>= 1) {
    a0 += __shfl_down(a0, off);
    a1 += __shfl_down(a1, off);
    a2 += __shfl_down(a2, off);
    a3 += __shfl_down(a3, off);
  }
  if (lane == 0) {
    float4 r; r.x = a0; r.y = a1; r.z = a2; r.w = a3;
    ((float4*)p1)[m] = r;
  }
}

// p2[m, i*4+r] = dot(hact[m, r*1024:...], x[b, 10+2i, :]). Wave per row; grid 2048.
__global__ __launch_bounds__(256) void p2_kernel(const unsigned short* __restrict__ hact,
                                                 const float* __restrict__ x,
                                                 float* __restrict__ p2) {
  const int wave = threadIdx.x >> 6, lane = threadIdx.x & 63;
  const int m = blockIdx.x * 4 + wave;
  const int b = m >> 11;
  const ushort4* hrow4 = (const ushort4*)(hact + (size_t)m * HDIM);
  const float4* od4    = (const float4*)(x + ((size_t)b * 2048 + 10) * DDIM);
  float acc[4][4] = {{0.f}};
#pragma unroll
  for (int it = 0; it < 4; ++it) {
    int g = it * 64 + lane;           // 4-elem group 0..255 within 1024
    float h[4][4];
#pragma unroll
    for (int r = 0; r < 4; ++r) {
      ushort4 hv = hrow4[r * 256 + g];
      h[r][0] = bf2f(hv.x); h[r][1] = bf2f(hv.y); h[r][2] = bf2f(hv.z); h[r][3] = bf2f(hv.w);
    }
#pragma unroll
    for (int i = 0; i < 4; ++i) {
      float4 ov = od4[i * 512 + g];
#pragma unroll
      for (int r = 0; r < 4; ++r)
        acc[i][r] += ov.x * h[r][0] + ov.y * h[r][1] + ov.z * h[r][2] + ov.w * h[r][3];
    }
  }
#pragma unroll
  for (int i = 0; i < 4; ++i)
#pragma unroll
    for (int r = 0; r < 4; ++r)
#pragma unroll
      for (int off = 32; off > 0; off >>= 1)
        acc[i][r] += __shfl_down(acc[i][r], off);
  if (lane == 0) {
#pragma unroll
    for (int i = 0; i < 4; ++i) {
      float4 v; v.x = acc[i][0]; v.y = acc[i][1]; v.z = acc[i][2]; v.w = acc[i][3];
      ((float4*)(p2 + (size_t)m * 16))[i] = v;
    }
  }
}

// BK=64 mainloop: C(128x128) = A(128xK) . B(128xK)^T, bf16 in, fp32 acc.
// LDS 2x16KB. Chunk swizzle: LDS slot s of row r holds global 16B-chunk
// c = (s - r) & 7; reader of chunk c uses slot (c + r) & 7. Spreads both the
// b128 frag reads and keeps global_load_lds's forced lane-contiguous dest legal
// (we permute the SOURCE pointer per lane, never the LDS destination).
__device__ __forceinline__ void gemm_bt_tile(const unsigned short* __restrict__ A,
                                             const unsigned short* __restrict__ B,
                                             const int K, const int m0, const int n0,
                                             unsigned short* As, unsigned short* Bs,
                                             f32x4 acc[4][4]) {
  const int tid  = threadIdx.x;
  const int wave = tid >> 6;
  const int lane = tid & 63;
  const int quad = lane >> 4;
  const int l16  = lane & 15;
  const int wm   = (wave >> 1) * 64;
  const int wn   = (wave & 1) * 64;

  // staging: 1024 16B-chunks per tile (128 rows x 8 slots); 4 wave-loads each
  const unsigned short* ga[4]; const unsigned short* gb[4];
#pragma unroll
  for (int s = 0; s < 4; ++s) {
    int idx = wave * 256 + s * 64 + lane;   // linear LDS 16B-slot
    int r = idx >> 3, sl = idx & 7;
    int c = (sl - r) & 7;                   // global chunk stored at this slot
    ga[s] = A + (size_t)(m0 + r) * K + c * 8;
    gb[s] = B + (size_t)(n0 + r) * K + c * 8;
  }

  for (int k0 = 0; k0 < K; k0 += 64) {
    __syncthreads();
#pragma unroll
    for (int s = 0; s < 4; ++s) gld_lds16(ga[s] + k0, As + (wave * 4 + s) * 512);
#pragma unroll
    for (int s = 0; s < 4; ++s) gld_lds16(gb[s] + k0, Bs + (wave * 4 + s) * 512);
    __syncthreads();
#pragma unroll
    for (int kk = 0; kk < 64; kk += 32) {
      bf16x8 a[4], b[4];
      const int cbase = (kk >> 3) + quad;   // global chunk of this frag
#pragma unroll
      for (int i = 0; i < 4; ++i) {
        const int ra = wm + i * 16 + l16;
        const int rb = wn + i * 16 + l16;
        a[i] = *(const bf16x8*)(As + ra * 64 + ((cbase + ra) & 7) * 8);
        b[i] = *(const bf16x8*)(Bs + rb * 64 + ((cbase + rb) & 7) * 8);
      }
#pragma unroll
      for (int i = 0; i < 4; ++i)
#pragma unroll
        for (int j = 0; j < 4; ++j)
          acc[i][j] = __builtin_amdgcn_mfma_f32_16x16x32_bf16(a[i], b[j], acc[i][j], 0, 0, 0);
    }
  }
}

// GEMM1: hact = gelu( x.W1^T + b1 + scale*p1*even ),  M=8192 N=4096 K=1024, out bf16
__global__ __launch_bounds__(256) void gemm1_kernel(
    const unsigned short* __restrict__ xb, const unsigned short* __restrict__ w1b,
    const float* __restrict__ x, const float* __restrict__ b1,
    const float* __restrict__ p1, const float* __restrict__ scale_p,
    unsigned short* __restrict__ hact) {
  __shared__ __align__(16) unsigned short As[128 * 64];
  __shared__ __align__(16) unsigned short Bs[128 * 64];
  const int n0 = blockIdx.x * 128;
  const int m0 = blockIdx.y * 128;
  f32x4 acc[4][4];
  const f32x4 z = {0.f, 0.f, 0.f, 0.f};
#pragma unroll
  for (int i = 0; i < 4; ++i)
#pragma unroll
    for (int j = 0; j < 4; ++j) acc[i][j] = z;

  gemm_bt_tile(xb, w1b, DDIM, m0, n0, As, Bs, acc);

  const int tid = threadIdx.x;
  const int wave = tid >> 6, lane = tid & 63, quad = lane >> 4, l16 = lane & 15;
  const int wm = (wave >> 1) * 64, wn = (wave & 1) * 64;
  const float sc = scale_p[0];
  const int bidx = m0 >> 11;
  const int i1 = (n0 + wn) >> 10;            // wave-uniform lora index
  const float* exrow = x + ((size_t)(bidx * 2048 + 1 + 2 * i1)) * DDIM;

  float exv[4], b1v[4]; int nn[4];
#pragma unroll
  for (int j = 0; j < 4; ++j) {
    nn[j]  = n0 + wn + j * 16 + l16;
    exv[j] = exrow[nn[j] & 1023];
    b1v[j] = b1[nn[j]];
  }
#pragma unroll
  for (int i = 0; i < 4; ++i) {
#pragma unroll
    for (int r = 0; r < 4; ++r) {
      const int m = m0 + wm + i * 16 + quad * 4 + r;
      const float pv = p1[(size_t)m * 4 + i1] * sc;
#pragma unroll
      for (int j = 0; j < 4; ++j) {
        float v = acc[i][j][r] + b1v[j] + pv * exv[j];
        hact[(size_t)m * HDIM + nn[j]] = f2bf(fast_gelu(v));
      }
    }
  }
}

// GEMM2: out = hact.W2^T + b2 + scale*<even2_4q, p2[m,i2,:]>,  M=8192 N=1024 K=4096
__global__ __launch_bounds__(256) void gemm2_kernel(
    const unsigned short* __restrict__ hact, const unsigned short* __restrict__ w2b,
    const float* __restrict__ x, const float* __restrict__ b2,
    const float* __restrict__ p2, const float* __restrict__ scale_p,
    float* __restrict__ out) {
  __shared__ __align__(16) unsigned short As[128 * 64];
  __shared__ __align__(16) unsigned short Bs[128 * 64];
  const int n0 = blockIdx.x * 128;
  const int m0 = blockIdx.y * 128;
  f32x4 acc[4][4];
  const f32x4 z = {0.f, 0.f, 0.f, 0.f};
#pragma unroll
  for (int i = 0; i < 4; ++i)
#pragma unroll
    for (int j = 0; j < 4; ++j) acc[i][j] = z;

  gemm_bt_tile(hact, w2b, HDIM, m0, n0, As, Bs, acc);

  const int tid = threadIdx.x;
  const int wave = tid >> 6, lane = tid & 63, quad = lane >> 4, l16 = lane & 15;
  const int wm = (wave >> 1) * 64, wn = (wave & 1) * 64;
  const float sc = scale_p[0];
  const int bidx = m0 >> 11;
  const int i2 = (n0 + wn) >> 8;             // wave-uniform
  const float* evrow = x + ((size_t)(bidx * 2048 + 9 + 2 * i2)) * DDIM;

  float4 ev[4]; float b2v[4]; int nn[4];
#pragma unroll
  for (int j = 0; j < 4; ++j) {
    nn[j] = n0 + wn + j * 16 + l16;
    const int q = nn[j] & 255;
    ev[j]  = *(const float4*)(evrow + 4 * q);
    b2v[j] = b2[nn[j]];
  }
#pragma unroll
  for (int i = 0; i < 4; ++i) {
#pragma unroll
    for (int r = 0; r < 4; ++r) {
      const int m = m0 + wm + i * 16 + quad * 4 + r;
      const float4 pv = *(const float4*)(p2 + (size_t)m * 16 + i2 * 4);
#pragma unroll
      for (int j = 0; j < 4; ++j) {
        float lora = ev[j].x * pv.x + ev[j].y * pv.y + ev[j].z * pv.z + ev[j].w * pv.w;
        out[(size_t)m * DDIM + nn[j]] = acc[i][j][r] + b2v[j] + sc * lora;
      }
    }
  }
}

extern "C" void kernel_launch(void* const* d_in, const int* in_sizes, int n_in,
                              void* d_out, int out_size, void* d_ws, size_t ws_size,
                              hipStream_t stream) {
  const float* x     = (const float*)d_in[0];
  const float* W1    = (const float*)d_in[1];
  const float* b1    = (const float*)d_in[2];
  const float* W2    = (const float*)d_in[3];
  const float* b2    = (const float*)d_in[4];
  const float* scale = (const float*)d_in[5];
  float* out = (float*)d_out;

  char* ws = (char*)d_ws;
  unsigned short* xb   = (unsigned short*)(ws);                // 16 MiB
  unsigned short* w1b  = (unsigned short*)(ws + 16777216);     //  8 MiB
  unsigned short* w2b  = (unsigned short*)(ws + 25165824);     //  8 MiB
  unsigned short* hact = (unsigned short*)(ws + 33554432);     // 64 MiB
  float*          p1   = (float*)(ws + 100663296);             // 128 KiB
  float*          p2   = (float*)(ws + 100794368);             // 512 KiB

  cvt2_kernel<<<dim3(8192), dim3(256), 0, stream>>>(W1, W2, w1b, w2b);
  p1_kernel<<<dim3(MROWS / 4), dim3(256), 0, stream>>>(x, p1, xb);
  gemm1_kernel<<<dim3(HDIM / 128, MROWS / 128), dim3(256), 0, stream>>>(xb, w1b, x, b1, p1, scale, hact);
  p2_kernel<<<dim3(MROWS / 4), dim3(256), 0, stream>>>(hact, x, p2);
  gemm2_kernel<<<dim3(DDIM / 128, MROWS / 128), dim3(256), 0, stream>>>(hact, w2b, x, b2, p2, scale, out);
}